// Round 7
// baseline (442.721 us; speedup 1.0000x reference)
//
#include <hip/hip_runtime.h>

// Problem constants
constexpr int B_N = 4;
constexpr int C_N = 3;
constexpr int H_IMG = 720;
constexpr int W_IMG = 1280;
constexpr int HW = H_IMG * W_IMG;
// KERNEL_RADIUS=4, KERNEL_SIGMA2=0.5 -> w = exp(-d2)

// Gather tiling: block owns 64x64 targets; thread owns 8 (x) * 2 (y) targets.
// R2 lesson: 320-thread blocks -> compiler throttled VGPR to 68 -> spills.
// R3 lesson: inline-asm v_pk_*_f32 -> odd-aligned VGPR pairs -> NaN. Banned.
// R4 lesson: fewer LDS/VALU issues != faster at 2 waves/SIMD (stall-bound).
// R5/R6 lesson: VGPR budget is derived from LDS-implied occupancy, NOT from
//   __launch_bounds__ min-waves. 30.7KB LDS -> target 5 waves/EU -> budget
//   ~102 -> spill-collapse to VGPR=60. Fix: pin target to 4 waves/EU via
//   amdgpu_waves_per_eu(4,4) AND pad LDS past 32768B so the LDS-derived cap
//   is also 4 -> budget exactly 128 (proven spill-free in R1/R4).
constexpr int TW = 64, TH = 64;
constexpr int THREADS = 256;
constexpr int HALO = 7;                 // R(4) + flow slack (3.5)
constexpr int CW = TW + 2 * HALO;       // 78
constexpr int CH = TH + 2 * HALO;       // 78 coverage rows total
constexpr int CHUNK = 39;               // rows per LDS chunk; 2 chunks = 78
constexpr int PITCH = 78;               // even (aligned h2 pairs), odd word-stride
constexpr int PLANE = CHUNK * PITCH;    // 3042 halfs used per plane
constexpr int PLANE_A = PLANE + 310;    // +620B pad/plane: 5 planes = 33.5KB
                                        // > 32768B -> LDS caps CU at 4 blocks
constexpr float FLOW_MAX = 3.5f;
constexpr float LOG2E = 1.44269504f;
constexpr float MARKER = -30.0f;        // all weights underflow to 0, temps finite

typedef _Float16 h2 __attribute__((ext_vector_type(2)));
typedef float f32x2 __attribute__((ext_vector_type(2)));
#define PKRTZ(a, b) __builtin_bit_cast(h2, __builtin_amdgcn_cvt_pkrtz((a), (b)))

// Forward-chain ratio constants: r_i = G * e^{-(2i+1)}, i = 0..6
constexpr float CE[7] = {
    0.36787944117144233f,   // e^-1
    0.049787068367863944f,  // e^-3
    0.006737946999085467f,  // e^-5
    0.0009118819655545162f, // e^-7
    0.00012340980408667956f,// e^-9
    1.670170079024566e-05f, // e^-11
    2.2603294069810542e-06f // e^-13
};

__global__ __launch_bounds__(THREADS)
__attribute__((amdgpu_waves_per_eu(4, 4)))   // VGPR budget 512/4 = 128 exactly
void gather_kernel(const float* __restrict__ src, const float* __restrict__ flow,
                   float* __restrict__ out) {
    __shared__ _Float16 Up[PLANE_A], Vp[PLANE_A], P0[PLANE_A], P1[PLANE_A],
                        P2[PLANE_A];

    const int b = blockIdx.z;
    const int tx0 = blockIdx.x * TW;
    const int ty0 = blockIdx.y * TH;
    const int cx0 = tx0 - HALO, cy0 = ty0 - HALO;

    const float* __restrict__ up = flow + (size_t)(b * 2) * HW;
    const float* __restrict__ vp = up + HW;
    const float* __restrict__ sp = src + (size_t)(b * 3) * HW;

    const int xg = threadIdx.x & 7;     // 8 x-groups of 8 targets
    const int yg = threadIdx.x >> 3;    // 32 row-pairs
    const int ty_a = ty0 + 2 * yg;
    const bool live = (ty_a < H_IMG);   // tail blocks: rows >= 720 discarded

    float aW[2][8], a0[2][8], a1[2][8], a2[2][8];
#pragma unroll
    for (int j = 0; j < 2; ++j)
#pragma unroll
        for (int i = 0; i < 8; ++i) { aW[j][i] = 0.f; a0[j][i] = 0.f;
                                      a1[j][i] = 0.f; a2[j][i] = 0.f; }

    // Two phases: stage cell rows [lo, lo+CHUNK), compute the oy's whose
    // cell row 2*yg+oy falls in the chunk. Each cell row is staged exactly
    // once; per-thread oy order stays 0..15 ascending -> bit-identical sums.
    for (int phase = 0; phase < 2; ++phase) {
        const int lo = phase * CHUNK;

        if (phase) __syncthreads();     // compute of prev chunk must finish

        // Stage this chunk as 5 f16 planes. Invalid / outlier cells -> MARKER
        // (their weights underflow to 0; outliers were pre-splatted).
        for (int idx = threadIdx.x; idx < CHUNK * CW; idx += THREADS) {
            const int cr = idx / CW, cx = idx - cr * CW;
            const int gx = cx0 + cx, gy = cy0 + lo + cr;
            float u = MARKER, v = MARKER, s0 = 0.f, s1 = 0.f, s2 = 0.f;
            if (gx >= 0 && gx < W_IMG && gy >= 0 && gy < H_IMG) {
                const int g = gy * W_IMG + gx;
                const float uu = up[g], vv = vp[g];
                if (fabsf(uu) <= FLOW_MAX && fabsf(vv) <= FLOW_MAX) {
                    u = uu; v = vv;
                    s0 = sp[g]; s1 = sp[HW + g]; s2 = sp[2 * HW + g];
                }
            }
            const int l = cr * PITCH + cx;
            Up[l] = (_Float16)u; Vp[l] = (_Float16)v;
            P0[l] = (_Float16)s0; P1[l] = (_Float16)s1; P2[l] = (_Float16)s2;
        }
        __syncthreads();

        if (!live) continue;            // still hits both barriers each phase

        // This thread's cell rows are 2*yg+oy, oy in [0,16). Intersect with
        // [lo, lo+CHUNK) -> contiguous oy sub-range.
        const int oy_lo = max(0, lo - 2 * yg);
        const int oy_hi = min(16, lo + CHUNK - 2 * yg);

        for (int oy = oy_lo; oy < oy_hi; ++oy) {
            const float Cy = (float)(oy - 7);
            const int lrow = (2 * yg + oy - lo) * PITCH + 8 * xg;   // even
#pragma unroll
            for (int oxp = 0; oxp < 11; ++oxp) {           // 22 cells = 11 pairs
                const int l = lrow + 2 * oxp;
                const h2 u2 = *(const h2*)(Up + l);
                const h2 v2 = *(const h2*)(Vp + l);
                const h2 s02 = *(const h2*)(P0 + l);
                const h2 s12 = *(const h2*)(P1 + l);
                const h2 s22 = *(const h2*)(P2 + l);

                f32x2 uf, vf;
                uf.x = (float)u2.x; uf.y = (float)u2.y;
                vf.x = (float)v2.x; vf.y = (float)v2.y;

                // ---- x chains, forward-only: dx0 = cell_x - target0_x + u ----
                const f32x2 kx = {(float)(2 * oxp - 7), (float)(2 * oxp - 6)};
                const f32x2 dx0 = uf + kx;
                const f32x2 aL = dx0 * (-LOG2E);
                const f32x2 axx = aL * dx0;
                const f32x2 s2m = aL + aL;
                f32x2 w[8];
                w[0].x = __builtin_amdgcn_exp2f(axx.x);     // exp(-dx0^2)
                w[0].y = __builtin_amdgcn_exp2f(axx.y);
                f32x2 G;
                G.x = __builtin_amdgcn_exp2f(-s2m.x);       // exp(2*dx0)
                G.y = __builtin_amdgcn_exp2f(-s2m.y);

#pragma unroll
                for (int i = 0; i < 7; ++i)
                    w[i + 1] = w[i] * (G * CE[i]);

                h2 w2[8];
#pragma unroll
                for (int i = 0; i < 8; ++i)
                    w2[i] = PKRTZ(w[i].x, w[i].y);

                // ---- y weights (rows a,b), direct exps ----
                const f32x2 dy  = vf + Cy;
                const f32x2 dyb = dy - 1.f;
                const f32x2 bL = dy * (-LOG2E);
                const f32x2 cL = dyb * (-LOG2E);
                const f32x2 ya = bL * dy;
                const f32x2 yb = cL * dyb;
                const float eyaA = __builtin_amdgcn_exp2f(ya.x);
                const float eyaB = __builtin_amdgcn_exp2f(ya.y);
                const float eybA = __builtin_amdgcn_exp2f(yb.x);
                const float eybB = __builtin_amdgcn_exp2f(yb.y);

                const h2 eya2 = PKRTZ(eyaA, eyaB);
                const h2 eyb2 = PKRTZ(eybA, eybB);
                const h2 z0a = s02 * eya2, z0b = s02 * eyb2;
                const h2 z1a = s12 * eya2, z1b = s12 * eyb2;
                const h2 z2a = s22 * eya2, z2b = s22 * eyb2;

#pragma unroll
                for (int i = 0; i < 8; ++i) {
                    aW[0][i] = __builtin_amdgcn_fdot2(w2[i], eya2, aW[0][i], false);
                    aW[1][i] = __builtin_amdgcn_fdot2(w2[i], eyb2, aW[1][i], false);
                    a0[0][i] = __builtin_amdgcn_fdot2(w2[i], z0a, a0[0][i], false);
                    a0[1][i] = __builtin_amdgcn_fdot2(w2[i], z0b, a0[1][i], false);
                    a1[0][i] = __builtin_amdgcn_fdot2(w2[i], z1a, a1[0][i], false);
                    a1[1][i] = __builtin_amdgcn_fdot2(w2[i], z1b, a1[1][i], false);
                    a2[0][i] = __builtin_amdgcn_fdot2(w2[i], z2a, a2[0][i], false);
                    a2[1][i] = __builtin_amdgcn_fdot2(w2[i], z2b, a2[1][i], false);
                }
            }
        }
    }

    if (!live) return;

    // Fused epilogue: add pre-splatted outlier contributions (already in out),
    // divide by (w+eps), write final image + mask. No finalize kernel.
    float* __restrict__ wI = out;
    float* __restrict__ wb = out + (size_t)B_N * C_N * HW;
    const int gx0 = tx0 + 8 * xg;
#pragma unroll
    for (int j = 0; j < 2; ++j) {
        const int ty = ty_a + j;
        if (ty >= H_IMG) continue;
        const int tb = ty * W_IMG + gx0;              // 16B-aligned
        float* p0 = wI + (size_t)(b * 3 + 0) * HW + tb;
        float* p1 = wI + (size_t)(b * 3 + 1) * HW + tb;
        float* p2 = wI + (size_t)(b * 3 + 2) * HW + tb;
        float* pw = wb + (size_t)b * HW + tb;
#pragma unroll
        for (int h = 0; h < 2; ++h) {                 // two float4 halves
            const float4 q0 = *(float4*)(p0 + 4 * h);
            const float4 q1 = *(float4*)(p1 + 4 * h);
            const float4 q2 = *(float4*)(p2 + 4 * h);
            const float4 qw = *(float4*)(pw + 4 * h);
            float wv[4] = {qw.x + aW[j][4*h+0], qw.y + aW[j][4*h+1],
                           qw.z + aW[j][4*h+2], qw.w + aW[j][4*h+3]};
            float inv[4];
#pragma unroll
            for (int t = 0; t < 4; ++t) inv[t] = 1.0f / (wv[t] + 1e-8f);
            *(float4*)(p0 + 4 * h) = make_float4(
                (q0.x + a0[j][4*h+0]) * inv[0], (q0.y + a0[j][4*h+1]) * inv[1],
                (q0.z + a0[j][4*h+2]) * inv[2], (q0.w + a0[j][4*h+3]) * inv[3]);
            *(float4*)(p1 + 4 * h) = make_float4(
                (q1.x + a1[j][4*h+0]) * inv[0], (q1.y + a1[j][4*h+1]) * inv[1],
                (q1.z + a1[j][4*h+2]) * inv[2], (q1.w + a1[j][4*h+3]) * inv[3]);
            *(float4*)(p2 + 4 * h) = make_float4(
                (q2.x + a2[j][4*h+0]) * inv[0], (q2.y + a2[j][4*h+1]) * inv[1],
                (q2.z + a2[j][4*h+2]) * inv[2], (q2.w + a2[j][4*h+3]) * inv[3]);
            *(float4*)(pw + 4 * h) = make_float4(
                wv[0] > 0.f ? 1.f : 0.f, wv[1] > 0.f ? 1.f : 0.f,
                wv[2] > 0.f ? 1.f : 0.f, wv[3] > 0.f ? 1.f : 0.f);
        }
    }
}

// Exact splat for rare sources with |u|>3.5 or |v|>3.5 (~9e-4 of pixels).
// Runs BEFORE gather on the zeroed out buffer; gather adds these in.
__global__ __launch_bounds__(256)
void outlier_kernel(const float* __restrict__ src, const float* __restrict__ flow,
                    float* __restrict__ out) {
    const int n4 = B_N * HW / 4;
    const int i4 = blockIdx.x * 256 + threadIdx.x;
    if (i4 >= n4) return;
    const int per_b = HW / 4;
    const int b = i4 / per_b;
    const int g0 = (i4 - b * per_b) * 4;
    const float* __restrict__ up = flow + (size_t)(b * 2) * HW;
    const float4 u4 = *(const float4*)(up + g0);
    const float4 v4 = *(const float4*)(up + HW + g0);
    const float um = fmaxf(fmaxf(fabsf(u4.x), fabsf(u4.y)), fmaxf(fabsf(u4.z), fabsf(u4.w)));
    const float vm = fmaxf(fmaxf(fabsf(v4.x), fabsf(v4.y)), fmaxf(fabsf(v4.z), fabsf(v4.w)));
    if (um <= FLOW_MAX && vm <= FLOW_MAX) return;

    const float uu[4] = {u4.x, u4.y, u4.z, u4.w};
    const float vv[4] = {v4.x, v4.y, v4.z, v4.w};
    const float* __restrict__ sp = src + (size_t)(b * 3) * HW;
    float* __restrict__ wI = out;
    float* __restrict__ wb = out + (size_t)B_N * C_N * HW;

    for (int k = 0; k < 4; ++k) {
        const float u = uu[k], v = vv[k];
        if (fabsf(u) <= FLOW_MAX && fabsf(v) <= FLOW_MAX) continue;
        const int g = g0 + k;
        const int x = g % W_IMG, y = g / W_IMG;
        const float px = (float)x + u, py = (float)y + v;
        if (!(px > -6.f && px < (float)W_IMG + 5.f &&
              py > -6.f && py < (float)H_IMG + 5.f)) continue;

        const float bxf = floorf(px), byf = floorf(py);
        const int bx = (int)bxf, by = (int)byf;
        const float s0 = sp[g], s1 = sp[HW + g], s2 = sp[2 * HW + g];

        for (int dyi = -4; dyi <= 4; ++dyi) {
            const int tyy = by + dyi;
            if (tyy < 0 || tyy >= H_IMG) continue;
            const float dyf = (byf + (float)dyi) - py;
            const float dy2 = dyf * dyf;
            for (int dxi = -4; dxi <= 4; ++dxi) {
                const int txx = bx + dxi;
                if (txx < 0 || txx >= W_IMG) continue;
                const float dxf = (bxf + (float)dxi) - px;
                const float d2 = fmaf(dxf, dxf, dy2);
                if (d2 > 16.f) continue;
                const float w = __expf(-d2);
                const int t = tyy * W_IMG + txx;
                atomicAdd(&wb[(size_t)b * HW + t], w);
                atomicAdd(&wI[(size_t)(b * 3 + 0) * HW + t], w * s0);
                atomicAdd(&wI[(size_t)(b * 3 + 1) * HW + t], w * s1);
                atomicAdd(&wI[(size_t)(b * 3 + 2) * HW + t], w * s2);
            }
        }
    }
}

extern "C" void kernel_launch(void* const* d_in, const int* in_sizes, int n_in,
                              void* d_out, int out_size, void* d_ws, size_t ws_size,
                              hipStream_t stream) {
    const float* src = (const float*)d_in[0];    // (4,3,720,1280) fp32
    const float* flow = (const float*)d_in[1];   // (4,2,720,1280) fp32
    float* out = (float*)d_out;                  // img (4,3,HW) ++ mask (4,1,HW)

    // 1) zero accumulators (out is poisoned 0xAA before every timed launch)
    (void)hipMemsetAsync(d_out, 0, (size_t)out_size * sizeof(float), stream);

    // 2) pre-splat rare large-flow sources with global atomics
    const int n4 = B_N * HW / 4;
    outlier_kernel<<<(n4 + 255) / 256, 256, 0, stream>>>(src, flow, out);

    // 3) gather everything else; fused add-prior + divide + mask epilogue
    dim3 grid(W_IMG / TW, (H_IMG + TH - 1) / TH, B_N);   // 20 x 12 x 4
    gather_kernel<<<grid, 256, 0, stream>>>(src, flow, out);
}

// Round 8
// 378.148 us; speedup vs baseline: 1.1708x; 1.1708x over previous
//
#include <hip/hip_runtime.h>

// Problem constants
constexpr int B_N = 4;
constexpr int C_N = 3;
constexpr int H_IMG = 720;
constexpr int W_IMG = 1280;
constexpr int HW = H_IMG * W_IMG;
// KERNEL_RADIUS=4, KERNEL_SIGMA2=0.5 -> w = exp(-d2)

// Gather tiling: block owns 64x64 targets; thread owns 8 (x) * 2 (y) targets.
// Session-verified optimum (R1 = 378us total, gather 240us, VGPR=128):
//   - 256 threads, __launch_bounds__(256,2), single-phase 60.9KB LDS.
// Failed arcs (do not revisit):
//   R2: 320-thread blocks -> VGPR throttled to 68 -> spills (427us).
//   R3: inline-asm v_pk_*_f32 -> odd-aligned VGPR pairs -> NaN.
//   R4: pair-major LDS (b64 reads) + tail-exit -> +5% (252us).
//   R5-R7: chunked 30KB LDS for occupancy -> accumulators live across
//     barriers + divergent CFG -> allocator collapses to VGPR=60 regardless
//     of launch_bounds / waves_per_eu / LDS padding -> 313us.
constexpr int TW = 64, TH = 64;
constexpr int THREADS = 256;
constexpr int HALO = 7;                 // R(4) + flow slack (3.5)
constexpr int CW = TW + 2 * HALO;       // 78
constexpr int CH = TH + 2 * HALO;       // 78
constexpr int PITCH = 78;               // even (aligned h2 pairs), odd word-stride
constexpr int PLANE = CH * PITCH;       // 6084 halfs/plane; 5 planes = 60.8 KB
constexpr float FLOW_MAX = 3.5f;
constexpr float LOG2E = 1.44269504f;
constexpr float MARKER = -30.0f;        // all weights underflow to 0, temps finite

typedef _Float16 h2 __attribute__((ext_vector_type(2)));
typedef float f32x2 __attribute__((ext_vector_type(2)));
#define PKRTZ(a, b) __builtin_bit_cast(h2, __builtin_amdgcn_cvt_pkrtz((a), (b)))

// Forward-chain ratio constants: r_i = G * e^{-(2i+1)}, i = 0..6
// constexpr (not __constant__) so they fold to inline literals, no memory op.
constexpr float CE[7] = {
    0.36787944117144233f,   // e^-1
    0.049787068367863944f,  // e^-3
    0.006737946999085467f,  // e^-5
    0.0009118819655545162f, // e^-7
    0.00012340980408667956f,// e^-9
    1.670170079024566e-05f, // e^-11
    2.2603294069810542e-06f // e^-13
};

__global__ __launch_bounds__(THREADS, 2)
void gather_kernel(const float* __restrict__ src, const float* __restrict__ flow,
                   float* __restrict__ out) {
    __shared__ _Float16 Up[PLANE], Vp[PLANE], P0[PLANE], P1[PLANE], P2[PLANE];

    const int b = blockIdx.z;
    const int tx0 = blockIdx.x * TW;
    const int ty0 = blockIdx.y * TH;
    const int cx0 = tx0 - HALO, cy0 = ty0 - HALO;

    const float* __restrict__ up = flow + (size_t)(b * 2) * HW;
    const float* __restrict__ vp = up + HW;
    const float* __restrict__ sp = src + (size_t)(b * 3) * HW;

    // Stage coverage as 5 f16 planes. Invalid / outlier cells -> MARKER
    // (their weights underflow to exactly 0; outliers were pre-splatted).
    for (int idx = threadIdx.x; idx < CH * CW; idx += THREADS) {
        const int cr = idx / CW, cx = idx - cr * CW;
        const int gx = cx0 + cx, gy = cy0 + cr;
        float u = MARKER, v = MARKER, s0 = 0.f, s1 = 0.f, s2 = 0.f;
        if (gx >= 0 && gx < W_IMG && gy >= 0 && gy < H_IMG) {
            const int g = gy * W_IMG + gx;
            const float uu = up[g], vv = vp[g];
            if (fabsf(uu) <= FLOW_MAX && fabsf(vv) <= FLOW_MAX) {
                u = uu; v = vv;
                s0 = sp[g]; s1 = sp[HW + g]; s2 = sp[2 * HW + g];
            }
        }
        const int l = cr * PITCH + cx;
        Up[l] = (_Float16)u; Vp[l] = (_Float16)v;
        P0[l] = (_Float16)s0; P1[l] = (_Float16)s1; P2[l] = (_Float16)s2;
    }
    __syncthreads();

    const int xg = threadIdx.x & 7;     // 8 x-groups of 8 targets
    const int yg = threadIdx.x >> 3;    // 32 row-pairs
    const int ty_a = ty0 + 2 * yg;

    float aW[2][8], a0[2][8], a1[2][8], a2[2][8];
#pragma unroll
    for (int j = 0; j < 2; ++j)
#pragma unroll
        for (int i = 0; i < 8; ++i) { aW[j][i] = 0.f; a0[j][i] = 0.f;
                                      a1[j][i] = 0.f; a2[j][i] = 0.f; }

    for (int oy = 0; oy < 16; ++oy) {
        const float Cy = (float)(oy - 7);
        const int lrow = (2 * yg + oy) * PITCH + 8 * xg;   // even
#pragma unroll
        for (int oxp = 0; oxp < 11; ++oxp) {               // 22 cells = 11 pairs
            const int l = lrow + 2 * oxp;
            const h2 u2 = *(const h2*)(Up + l);
            const h2 v2 = *(const h2*)(Vp + l);
            const h2 s02 = *(const h2*)(P0 + l);
            const h2 s12 = *(const h2*)(P1 + l);
            const h2 s22 = *(const h2*)(P2 + l);

            f32x2 uf, vf;
            uf.x = (float)u2.x; uf.y = (float)u2.y;
            vf.x = (float)v2.x; vf.y = (float)v2.y;

            // ---- x chains, forward-only: dx0 = cell_x - target0_x + u ----
            const f32x2 kx = {(float)(2 * oxp - 7), (float)(2 * oxp - 6)};
            const f32x2 dx0 = uf + kx;
            const f32x2 aL = dx0 * (-LOG2E);
            const f32x2 axx = aL * dx0;
            const f32x2 s2m = aL + aL;
            f32x2 w[8];
            w[0].x = __builtin_amdgcn_exp2f(axx.x);     // exp(-dx0^2)
            w[0].y = __builtin_amdgcn_exp2f(axx.y);
            f32x2 G;
            G.x = __builtin_amdgcn_exp2f(-s2m.x);       // exp(2*dx0)
            G.y = __builtin_amdgcn_exp2f(-s2m.y);

#pragma unroll
            for (int i = 0; i < 7; ++i)
                w[i + 1] = w[i] * (G * CE[i]);

            h2 w2[8];
#pragma unroll
            for (int i = 0; i < 8; ++i)
                w2[i] = PKRTZ(w[i].x, w[i].y);

            // ---- y weights (rows a,b), direct exps ----
            const f32x2 dy  = vf + Cy;
            const f32x2 dyb = dy - 1.f;
            const f32x2 bL = dy * (-LOG2E);
            const f32x2 cL = dyb * (-LOG2E);
            const f32x2 ya = bL * dy;
            const f32x2 yb = cL * dyb;
            const float eyaA = __builtin_amdgcn_exp2f(ya.x);
            const float eyaB = __builtin_amdgcn_exp2f(ya.y);
            const float eybA = __builtin_amdgcn_exp2f(yb.x);
            const float eybB = __builtin_amdgcn_exp2f(yb.y);

            const h2 eya2 = PKRTZ(eyaA, eyaB);
            const h2 eyb2 = PKRTZ(eybA, eybB);
            const h2 z0a = s02 * eya2, z0b = s02 * eyb2;
            const h2 z1a = s12 * eya2, z1b = s12 * eyb2;
            const h2 z2a = s22 * eya2, z2b = s22 * eyb2;

#pragma unroll
            for (int i = 0; i < 8; ++i) {
                aW[0][i] = __builtin_amdgcn_fdot2(w2[i], eya2, aW[0][i], false);
                aW[1][i] = __builtin_amdgcn_fdot2(w2[i], eyb2, aW[1][i], false);
                a0[0][i] = __builtin_amdgcn_fdot2(w2[i], z0a, a0[0][i], false);
                a0[1][i] = __builtin_amdgcn_fdot2(w2[i], z0b, a0[1][i], false);
                a1[0][i] = __builtin_amdgcn_fdot2(w2[i], z1a, a1[0][i], false);
                a1[1][i] = __builtin_amdgcn_fdot2(w2[i], z1b, a1[1][i], false);
                a2[0][i] = __builtin_amdgcn_fdot2(w2[i], z2a, a2[0][i], false);
                a2[1][i] = __builtin_amdgcn_fdot2(w2[i], z2b, a2[1][i], false);
            }
        }
    }

    // Fused epilogue: add pre-splatted outlier contributions (already in out),
    // divide by (w+eps), write final image + mask. No finalize kernel.
    float* __restrict__ wI = out;
    float* __restrict__ wb = out + (size_t)B_N * C_N * HW;
    const int gx0 = tx0 + 8 * xg;
#pragma unroll
    for (int j = 0; j < 2; ++j) {
        const int ty = ty_a + j;
        if (ty >= H_IMG) continue;
        const int tb = ty * W_IMG + gx0;              // 16B-aligned
        float* p0 = wI + (size_t)(b * 3 + 0) * HW + tb;
        float* p1 = wI + (size_t)(b * 3 + 1) * HW + tb;
        float* p2 = wI + (size_t)(b * 3 + 2) * HW + tb;
        float* pw = wb + (size_t)b * HW + tb;
#pragma unroll
        for (int h = 0; h < 2; ++h) {                 // two float4 halves
            const float4 q0 = *(float4*)(p0 + 4 * h);
            const float4 q1 = *(float4*)(p1 + 4 * h);
            const float4 q2 = *(float4*)(p2 + 4 * h);
            const float4 qw = *(float4*)(pw + 4 * h);
            float wv[4] = {qw.x + aW[j][4*h+0], qw.y + aW[j][4*h+1],
                           qw.z + aW[j][4*h+2], qw.w + aW[j][4*h+3]};
            float inv[4];
#pragma unroll
            for (int t = 0; t < 4; ++t) inv[t] = 1.0f / (wv[t] + 1e-8f);
            *(float4*)(p0 + 4 * h) = make_float4(
                (q0.x + a0[j][4*h+0]) * inv[0], (q0.y + a0[j][4*h+1]) * inv[1],
                (q0.z + a0[j][4*h+2]) * inv[2], (q0.w + a0[j][4*h+3]) * inv[3]);
            *(float4*)(p1 + 4 * h) = make_float4(
                (q1.x + a1[j][4*h+0]) * inv[0], (q1.y + a1[j][4*h+1]) * inv[1],
                (q1.z + a1[j][4*h+2]) * inv[2], (q1.w + a1[j][4*h+3]) * inv[3]);
            *(float4*)(p2 + 4 * h) = make_float4(
                (q2.x + a2[j][4*h+0]) * inv[0], (q2.y + a2[j][4*h+1]) * inv[1],
                (q2.z + a2[j][4*h+2]) * inv[2], (q2.w + a2[j][4*h+3]) * inv[3]);
            *(float4*)(pw + 4 * h) = make_float4(
                wv[0] > 0.f ? 1.f : 0.f, wv[1] > 0.f ? 1.f : 0.f,
                wv[2] > 0.f ? 1.f : 0.f, wv[3] > 0.f ? 1.f : 0.f);
        }
    }
}

// Exact splat for rare sources with |u|>3.5 or |v|>3.5 (~9e-4 of pixels).
// Runs BEFORE gather on the zeroed out buffer; gather adds these in.
__global__ __launch_bounds__(256)
void outlier_kernel(const float* __restrict__ src, const float* __restrict__ flow,
                    float* __restrict__ out) {
    const int n4 = B_N * HW / 4;
    const int i4 = blockIdx.x * 256 + threadIdx.x;
    if (i4 >= n4) return;
    const int per_b = HW / 4;
    const int b = i4 / per_b;
    const int g0 = (i4 - b * per_b) * 4;
    const float* __restrict__ up = flow + (size_t)(b * 2) * HW;
    const float4 u4 = *(const float4*)(up + g0);
    const float4 v4 = *(const float4*)(up + HW + g0);
    const float um = fmaxf(fmaxf(fabsf(u4.x), fabsf(u4.y)), fmaxf(fabsf(u4.z), fabsf(u4.w)));
    const float vm = fmaxf(fmaxf(fabsf(v4.x), fabsf(v4.y)), fmaxf(fabsf(v4.z), fabsf(v4.w)));
    if (um <= FLOW_MAX && vm <= FLOW_MAX) return;

    const float uu[4] = {u4.x, u4.y, u4.z, u4.w};
    const float vv[4] = {v4.x, v4.y, v4.z, v4.w};
    const float* __restrict__ sp = src + (size_t)(b * 3) * HW;
    float* __restrict__ wI = out;
    float* __restrict__ wb = out + (size_t)B_N * C_N * HW;

    for (int k = 0; k < 4; ++k) {
        const float u = uu[k], v = vv[k];
        if (fabsf(u) <= FLOW_MAX && fabsf(v) <= FLOW_MAX) continue;
        const int g = g0 + k;
        const int x = g % W_IMG, y = g / W_IMG;
        const float px = (float)x + u, py = (float)y + v;
        if (!(px > -6.f && px < (float)W_IMG + 5.f &&
              py > -6.f && py < (float)H_IMG + 5.f)) continue;

        const float bxf = floorf(px), byf = floorf(py);
        const int bx = (int)bxf, by = (int)byf;
        const float s0 = sp[g], s1 = sp[HW + g], s2 = sp[2 * HW + g];

        for (int dyi = -4; dyi <= 4; ++dyi) {
            const int tyy = by + dyi;
            if (tyy < 0 || tyy >= H_IMG) continue;
            const float dyf = (byf + (float)dyi) - py;
            const float dy2 = dyf * dyf;
            for (int dxi = -4; dxi <= 4; ++dxi) {
                const int txx = bx + dxi;
                if (txx < 0 || txx >= W_IMG) continue;
                const float dxf = (bxf + (float)dxi) - px;
                const float d2 = fmaf(dxf, dxf, dy2);
                if (d2 > 16.f) continue;
                const float w = __expf(-d2);
                const int t = tyy * W_IMG + txx;
                atomicAdd(&wb[(size_t)b * HW + t], w);
                atomicAdd(&wI[(size_t)(b * 3 + 0) * HW + t], w * s0);
                atomicAdd(&wI[(size_t)(b * 3 + 1) * HW + t], w * s1);
                atomicAdd(&wI[(size_t)(b * 3 + 2) * HW + t], w * s2);
            }
        }
    }
}

extern "C" void kernel_launch(void* const* d_in, const int* in_sizes, int n_in,
                              void* d_out, int out_size, void* d_ws, size_t ws_size,
                              hipStream_t stream) {
    const float* src = (const float*)d_in[0];    // (4,3,720,1280) fp32
    const float* flow = (const float*)d_in[1];   // (4,2,720,1280) fp32
    float* out = (float*)d_out;                  // img (4,3,HW) ++ mask (4,1,HW)

    // 1) zero accumulators (out is poisoned 0xAA before every timed launch)
    (void)hipMemsetAsync(d_out, 0, (size_t)out_size * sizeof(float), stream);

    // 2) pre-splat rare large-flow sources with global atomics
    const int n4 = B_N * HW / 4;
    outlier_kernel<<<(n4 + 255) / 256, 256, 0, stream>>>(src, flow, out);

    // 3) gather everything else; fused add-prior + divide + mask epilogue
    dim3 grid(W_IMG / TW, (H_IMG + TH - 1) / TH, B_N);   // 20 x 12 x 4
    gather_kernel<<<grid, 256, 0, stream>>>(src, flow, out);
}

// Round 9
// 360.004 us; speedup vs baseline: 1.2298x; 1.0504x over previous
//
#include <hip/hip_runtime.h>

// Problem constants
constexpr int B_N = 4;
constexpr int C_N = 3;
constexpr int H_IMG = 720;
constexpr int W_IMG = 1280;
constexpr int HW = H_IMG * W_IMG;
// KERNEL_RADIUS=4, KERNEL_SIGMA2=0.5 -> w = exp(-d2)

// Gather tiling: block owns 64x64 targets; thread owns 8 (x) * 2 (y) targets.
// Session-verified optimum body (R1/R8 = 378us total, gather 242us, VGPR=128):
//   256 threads, __launch_bounds__(256,2), single-phase 60.9KB LDS.
// Failed arcs (do not revisit):
//   R2: 320-thread blocks -> VGPR throttled to 68 -> spills (427us).
//   R3: inline-asm v_pk_*_f32 -> odd-aligned VGPR pairs -> NaN.
//   R4: pair-major LDS (b64 reads) + tail-exit -> +5% (252us).
//   R5-R7: chunked 30KB LDS for occupancy -> allocator collapses to VGPR=60
//     regardless of launch_bounds / waves_per_eu / LDS padding -> 313us.
// R9 lever: LDS caps occupancy at 2 blocks/CU, so VGPR 128..256 is FREE.
//   #pragma unroll 2 on the oy loop doubles in-flight independent work
//   (ds_reads + exp chains of row oy+1 overlap row oy's fdot2 block).
constexpr int TW = 64, TH = 64;
constexpr int THREADS = 256;
constexpr int HALO = 7;                 // R(4) + flow slack (3.5)
constexpr int CW = TW + 2 * HALO;       // 78
constexpr int CH = TH + 2 * HALO;       // 78
constexpr int PITCH = 78;               // even (aligned h2 pairs), odd word-stride
constexpr int PLANE = CH * PITCH;       // 6084 halfs/plane; 5 planes = 60.8 KB
constexpr float FLOW_MAX = 3.5f;
constexpr float LOG2E = 1.44269504f;
constexpr float MARKER = -30.0f;        // all weights underflow to 0, temps finite

typedef _Float16 h2 __attribute__((ext_vector_type(2)));
typedef float f32x2 __attribute__((ext_vector_type(2)));
#define PKRTZ(a, b) __builtin_bit_cast(h2, __builtin_amdgcn_cvt_pkrtz((a), (b)))

// Forward-chain ratio constants: r_i = G * e^{-(2i+1)}, i = 0..6
// constexpr (not __constant__) so they fold to inline literals, no memory op.
constexpr float CE[7] = {
    0.36787944117144233f,   // e^-1
    0.049787068367863944f,  // e^-3
    0.006737946999085467f,  // e^-5
    0.0009118819655545162f, // e^-7
    0.00012340980408667956f,// e^-9
    1.670170079024566e-05f, // e^-11
    2.2603294069810542e-06f // e^-13
};

__global__ __launch_bounds__(THREADS, 2)
void gather_kernel(const float* __restrict__ src, const float* __restrict__ flow,
                   float* __restrict__ out) {
    __shared__ _Float16 Up[PLANE], Vp[PLANE], P0[PLANE], P1[PLANE], P2[PLANE];

    const int b = blockIdx.z;
    const int tx0 = blockIdx.x * TW;
    const int ty0 = blockIdx.y * TH;
    const int cx0 = tx0 - HALO, cy0 = ty0 - HALO;

    const float* __restrict__ up = flow + (size_t)(b * 2) * HW;
    const float* __restrict__ vp = up + HW;
    const float* __restrict__ sp = src + (size_t)(b * 3) * HW;

    // Stage coverage as 5 f16 planes. Invalid / outlier cells -> MARKER
    // (their weights underflow to exactly 0; outliers were pre-splatted).
    for (int idx = threadIdx.x; idx < CH * CW; idx += THREADS) {
        const int cr = idx / CW, cx = idx - cr * CW;
        const int gx = cx0 + cx, gy = cy0 + cr;
        float u = MARKER, v = MARKER, s0 = 0.f, s1 = 0.f, s2 = 0.f;
        if (gx >= 0 && gx < W_IMG && gy >= 0 && gy < H_IMG) {
            const int g = gy * W_IMG + gx;
            const float uu = up[g], vv = vp[g];
            if (fabsf(uu) <= FLOW_MAX && fabsf(vv) <= FLOW_MAX) {
                u = uu; v = vv;
                s0 = sp[g]; s1 = sp[HW + g]; s2 = sp[2 * HW + g];
            }
        }
        const int l = cr * PITCH + cx;
        Up[l] = (_Float16)u; Vp[l] = (_Float16)v;
        P0[l] = (_Float16)s0; P1[l] = (_Float16)s1; P2[l] = (_Float16)s2;
    }
    __syncthreads();

    const int xg = threadIdx.x & 7;     // 8 x-groups of 8 targets
    const int yg = threadIdx.x >> 3;    // 32 row-pairs
    const int ty_a = ty0 + 2 * yg;

    float aW[2][8], a0[2][8], a1[2][8], a2[2][8];
#pragma unroll
    for (int j = 0; j < 2; ++j)
#pragma unroll
        for (int i = 0; i < 8; ++i) { aW[j][i] = 0.f; a0[j][i] = 0.f;
                                      a1[j][i] = 0.f; a2[j][i] = 0.f; }

#pragma unroll 2
    for (int oy = 0; oy < 16; ++oy) {
        const float Cy = (float)(oy - 7);
        const int lrow = (2 * yg + oy) * PITCH + 8 * xg;   // even
#pragma unroll
        for (int oxp = 0; oxp < 11; ++oxp) {               // 22 cells = 11 pairs
            const int l = lrow + 2 * oxp;
            const h2 u2 = *(const h2*)(Up + l);
            const h2 v2 = *(const h2*)(Vp + l);
            const h2 s02 = *(const h2*)(P0 + l);
            const h2 s12 = *(const h2*)(P1 + l);
            const h2 s22 = *(const h2*)(P2 + l);

            f32x2 uf, vf;
            uf.x = (float)u2.x; uf.y = (float)u2.y;
            vf.x = (float)v2.x; vf.y = (float)v2.y;

            // ---- x chains, forward-only: dx0 = cell_x - target0_x + u ----
            const f32x2 kx = {(float)(2 * oxp - 7), (float)(2 * oxp - 6)};
            const f32x2 dx0 = uf + kx;
            const f32x2 aL = dx0 * (-LOG2E);
            const f32x2 axx = aL * dx0;
            const f32x2 s2m = aL + aL;
            f32x2 w[8];
            w[0].x = __builtin_amdgcn_exp2f(axx.x);     // exp(-dx0^2)
            w[0].y = __builtin_amdgcn_exp2f(axx.y);
            f32x2 G;
            G.x = __builtin_amdgcn_exp2f(-s2m.x);       // exp(2*dx0)
            G.y = __builtin_amdgcn_exp2f(-s2m.y);

#pragma unroll
            for (int i = 0; i < 7; ++i)
                w[i + 1] = w[i] * (G * CE[i]);

            h2 w2[8];
#pragma unroll
            for (int i = 0; i < 8; ++i)
                w2[i] = PKRTZ(w[i].x, w[i].y);

            // ---- y weights (rows a,b), direct exps ----
            const f32x2 dy  = vf + Cy;
            const f32x2 dyb = dy - 1.f;
            const f32x2 bL = dy * (-LOG2E);
            const f32x2 cL = dyb * (-LOG2E);
            const f32x2 ya = bL * dy;
            const f32x2 yb = cL * dyb;
            const float eyaA = __builtin_amdgcn_exp2f(ya.x);
            const float eyaB = __builtin_amdgcn_exp2f(ya.y);
            const float eybA = __builtin_amdgcn_exp2f(yb.x);
            const float eybB = __builtin_amdgcn_exp2f(yb.y);

            const h2 eya2 = PKRTZ(eyaA, eyaB);
            const h2 eyb2 = PKRTZ(eybA, eybB);
            const h2 z0a = s02 * eya2, z0b = s02 * eyb2;
            const h2 z1a = s12 * eya2, z1b = s12 * eyb2;
            const h2 z2a = s22 * eya2, z2b = s22 * eyb2;

#pragma unroll
            for (int i = 0; i < 8; ++i) {
                aW[0][i] = __builtin_amdgcn_fdot2(w2[i], eya2, aW[0][i], false);
                aW[1][i] = __builtin_amdgcn_fdot2(w2[i], eyb2, aW[1][i], false);
                a0[0][i] = __builtin_amdgcn_fdot2(w2[i], z0a, a0[0][i], false);
                a0[1][i] = __builtin_amdgcn_fdot2(w2[i], z0b, a0[1][i], false);
                a1[0][i] = __builtin_amdgcn_fdot2(w2[i], z1a, a1[0][i], false);
                a1[1][i] = __builtin_amdgcn_fdot2(w2[i], z1b, a1[1][i], false);
                a2[0][i] = __builtin_amdgcn_fdot2(w2[i], z2a, a2[0][i], false);
                a2[1][i] = __builtin_amdgcn_fdot2(w2[i], z2b, a2[1][i], false);
            }
        }
    }

    // Fused epilogue: add pre-splatted outlier contributions (already in out),
    // divide by (w+eps), write final image + mask. No finalize kernel.
    float* __restrict__ wI = out;
    float* __restrict__ wb = out + (size_t)B_N * C_N * HW;
    const int gx0 = tx0 + 8 * xg;
#pragma unroll
    for (int j = 0; j < 2; ++j) {
        const int ty = ty_a + j;
        if (ty >= H_IMG) continue;
        const int tb = ty * W_IMG + gx0;              // 16B-aligned
        float* p0 = wI + (size_t)(b * 3 + 0) * HW + tb;
        float* p1 = wI + (size_t)(b * 3 + 1) * HW + tb;
        float* p2 = wI + (size_t)(b * 3 + 2) * HW + tb;
        float* pw = wb + (size_t)b * HW + tb;
#pragma unroll
        for (int h = 0; h < 2; ++h) {                 // two float4 halves
            const float4 q0 = *(float4*)(p0 + 4 * h);
            const float4 q1 = *(float4*)(p1 + 4 * h);
            const float4 q2 = *(float4*)(p2 + 4 * h);
            const float4 qw = *(float4*)(pw + 4 * h);
            float wv[4] = {qw.x + aW[j][4*h+0], qw.y + aW[j][4*h+1],
                           qw.z + aW[j][4*h+2], qw.w + aW[j][4*h+3]};
            float inv[4];
#pragma unroll
            for (int t = 0; t < 4; ++t) inv[t] = 1.0f / (wv[t] + 1e-8f);
            *(float4*)(p0 + 4 * h) = make_float4(
                (q0.x + a0[j][4*h+0]) * inv[0], (q0.y + a0[j][4*h+1]) * inv[1],
                (q0.z + a0[j][4*h+2]) * inv[2], (q0.w + a0[j][4*h+3]) * inv[3]);
            *(float4*)(p1 + 4 * h) = make_float4(
                (q1.x + a1[j][4*h+0]) * inv[0], (q1.y + a1[j][4*h+1]) * inv[1],
                (q1.z + a1[j][4*h+2]) * inv[2], (q1.w + a1[j][4*h+3]) * inv[3]);
            *(float4*)(p2 + 4 * h) = make_float4(
                (q2.x + a2[j][4*h+0]) * inv[0], (q2.y + a2[j][4*h+1]) * inv[1],
                (q2.z + a2[j][4*h+2]) * inv[2], (q2.w + a2[j][4*h+3]) * inv[3]);
            *(float4*)(pw + 4 * h) = make_float4(
                wv[0] > 0.f ? 1.f : 0.f, wv[1] > 0.f ? 1.f : 0.f,
                wv[2] > 0.f ? 1.f : 0.f, wv[3] > 0.f ? 1.f : 0.f);
        }
    }
}

// Exact splat for rare sources with |u|>3.5 or |v|>3.5 (~9e-4 of pixels).
// Runs BEFORE gather on the zeroed out buffer; gather adds these in.
__global__ __launch_bounds__(256)
void outlier_kernel(const float* __restrict__ src, const float* __restrict__ flow,
                    float* __restrict__ out) {
    const int n4 = B_N * HW / 4;
    const int i4 = blockIdx.x * 256 + threadIdx.x;
    if (i4 >= n4) return;
    const int per_b = HW / 4;
    const int b = i4 / per_b;
    const int g0 = (i4 - b * per_b) * 4;
    const float* __restrict__ up = flow + (size_t)(b * 2) * HW;
    const float4 u4 = *(const float4*)(up + g0);
    const float4 v4 = *(const float4*)(up + HW + g0);
    const float um = fmaxf(fmaxf(fabsf(u4.x), fabsf(u4.y)), fmaxf(fabsf(u4.z), fabsf(u4.w)));
    const float vm = fmaxf(fmaxf(fabsf(v4.x), fabsf(v4.y)), fmaxf(fabsf(v4.z), fabsf(v4.w)));
    if (um <= FLOW_MAX && vm <= FLOW_MAX) return;

    const float uu[4] = {u4.x, u4.y, u4.z, u4.w};
    const float vv[4] = {v4.x, v4.y, v4.z, v4.w};
    const float* __restrict__ sp = src + (size_t)(b * 3) * HW;
    float* __restrict__ wI = out;
    float* __restrict__ wb = out + (size_t)B_N * C_N * HW;

    for (int k = 0; k < 4; ++k) {
        const float u = uu[k], v = vv[k];
        if (fabsf(u) <= FLOW_MAX && fabsf(v) <= FLOW_MAX) continue;
        const int g = g0 + k;
        const int x = g % W_IMG, y = g / W_IMG;
        const float px = (float)x + u, py = (float)y + v;
        if (!(px > -6.f && px < (float)W_IMG + 5.f &&
              py > -6.f && py < (float)H_IMG + 5.f)) continue;

        const float bxf = floorf(px), byf = floorf(py);
        const int bx = (int)bxf, by = (int)byf;
        const float s0 = sp[g], s1 = sp[HW + g], s2 = sp[2 * HW + g];

        for (int dyi = -4; dyi <= 4; ++dyi) {
            const int tyy = by + dyi;
            if (tyy < 0 || tyy >= H_IMG) continue;
            const float dyf = (byf + (float)dyi) - py;
            const float dy2 = dyf * dyf;
            for (int dxi = -4; dxi <= 4; ++dxi) {
                const int txx = bx + dxi;
                if (txx < 0 || txx >= W_IMG) continue;
                const float dxf = (bxf + (float)dxi) - px;
                const float d2 = fmaf(dxf, dxf, dy2);
                if (d2 > 16.f) continue;
                const float w = __expf(-d2);
                const int t = tyy * W_IMG + txx;
                atomicAdd(&wb[(size_t)b * HW + t], w);
                atomicAdd(&wI[(size_t)(b * 3 + 0) * HW + t], w * s0);
                atomicAdd(&wI[(size_t)(b * 3 + 1) * HW + t], w * s1);
                atomicAdd(&wI[(size_t)(b * 3 + 2) * HW + t], w * s2);
            }
        }
    }
}

extern "C" void kernel_launch(void* const* d_in, const int* in_sizes, int n_in,
                              void* d_out, int out_size, void* d_ws, size_t ws_size,
                              hipStream_t stream) {
    const float* src = (const float*)d_in[0];    // (4,3,720,1280) fp32
    const float* flow = (const float*)d_in[1];   // (4,2,720,1280) fp32
    float* out = (float*)d_out;                  // img (4,3,HW) ++ mask (4,1,HW)

    // 1) zero accumulators (out is poisoned 0xAA before every timed launch)
    (void)hipMemsetAsync(d_out, 0, (size_t)out_size * sizeof(float), stream);

    // 2) pre-splat rare large-flow sources with global atomics
    const int n4 = B_N * HW / 4;
    outlier_kernel<<<(n4 + 255) / 256, 256, 0, stream>>>(src, flow, out);

    // 3) gather everything else; fused add-prior + divide + mask epilogue
    dim3 grid(W_IMG / TW, (H_IMG + TH - 1) / TH, B_N);   // 20 x 12 x 4
    gather_kernel<<<grid, 256, 0, stream>>>(src, flow, out);
}

// Round 10
// 359.779 us; speedup vs baseline: 1.2305x; 1.0006x over previous
//
#include <hip/hip_runtime.h>

// Problem constants
constexpr int B_N = 4;
constexpr int C_N = 3;
constexpr int H_IMG = 720;
constexpr int W_IMG = 1280;
constexpr int HW = H_IMG * W_IMG;
// KERNEL_RADIUS=4, KERNEL_SIGMA2=0.5 -> w = exp(-d2)

// Gather tiling: block owns 64x64 targets; thread owns 8 (x) * 2 (y) targets.
// Session-verified trajectory:
//   R1/R8 baseline: 256t, LB(256,2), single-phase 60.9KB LDS -> 242us, VGPR=128.
//   R9: #pragma unroll 2 on oy -> 223.5us (WIN): scheduler pairs adjacent-row
//       ds_reads (bank conflicts -41%: 6.76M->3.99M), overlaps exp chains;
//       VGPR dropped to 88 (tighter schedule).
// Failed arcs (do not revisit): 320t blocks (VGPR 68, spills); inline-asm
//   v_pk_*_f32 (NaN); pair-major b64 LDS (+5%); chunked-LDS occupancy
//   (allocator collapse to VGPR=60 regardless of hints).
// R10: unroll 4 — extend R9's mechanism; VGPR headroom 88->256 is free
//   (LDS is sole occupancy limiter at 2 blocks/CU).
constexpr int TW = 64, TH = 64;
constexpr int THREADS = 256;
constexpr int HALO = 7;                 // R(4) + flow slack (3.5)
constexpr int CW = TW + 2 * HALO;       // 78
constexpr int CH = TH + 2 * HALO;       // 78
constexpr int PITCH = 78;               // even (aligned h2 pairs), odd word-stride
constexpr int PLANE = CH * PITCH;       // 6084 halfs/plane; 5 planes = 60.8 KB
constexpr float FLOW_MAX = 3.5f;
constexpr float LOG2E = 1.44269504f;
constexpr float MARKER = -30.0f;        // all weights underflow to 0, temps finite

typedef _Float16 h2 __attribute__((ext_vector_type(2)));
typedef float f32x2 __attribute__((ext_vector_type(2)));
#define PKRTZ(a, b) __builtin_bit_cast(h2, __builtin_amdgcn_cvt_pkrtz((a), (b)))

// Forward-chain ratio constants: r_i = G * e^{-(2i+1)}, i = 0..6
// constexpr (not __constant__) so they fold to inline literals, no memory op.
constexpr float CE[7] = {
    0.36787944117144233f,   // e^-1
    0.049787068367863944f,  // e^-3
    0.006737946999085467f,  // e^-5
    0.0009118819655545162f, // e^-7
    0.00012340980408667956f,// e^-9
    1.670170079024566e-05f, // e^-11
    2.2603294069810542e-06f // e^-13
};

__global__ __launch_bounds__(THREADS, 2)
void gather_kernel(const float* __restrict__ src, const float* __restrict__ flow,
                   float* __restrict__ out) {
    __shared__ _Float16 Up[PLANE], Vp[PLANE], P0[PLANE], P1[PLANE], P2[PLANE];

    const int b = blockIdx.z;
    const int tx0 = blockIdx.x * TW;
    const int ty0 = blockIdx.y * TH;
    const int cx0 = tx0 - HALO, cy0 = ty0 - HALO;

    const float* __restrict__ up = flow + (size_t)(b * 2) * HW;
    const float* __restrict__ vp = up + HW;
    const float* __restrict__ sp = src + (size_t)(b * 3) * HW;

    // Stage coverage as 5 f16 planes. Invalid / outlier cells -> MARKER
    // (their weights underflow to exactly 0; outliers were pre-splatted).
    for (int idx = threadIdx.x; idx < CH * CW; idx += THREADS) {
        const int cr = idx / CW, cx = idx - cr * CW;
        const int gx = cx0 + cx, gy = cy0 + cr;
        float u = MARKER, v = MARKER, s0 = 0.f, s1 = 0.f, s2 = 0.f;
        if (gx >= 0 && gx < W_IMG && gy >= 0 && gy < H_IMG) {
            const int g = gy * W_IMG + gx;
            const float uu = up[g], vv = vp[g];
            if (fabsf(uu) <= FLOW_MAX && fabsf(vv) <= FLOW_MAX) {
                u = uu; v = vv;
                s0 = sp[g]; s1 = sp[HW + g]; s2 = sp[2 * HW + g];
            }
        }
        const int l = cr * PITCH + cx;
        Up[l] = (_Float16)u; Vp[l] = (_Float16)v;
        P0[l] = (_Float16)s0; P1[l] = (_Float16)s1; P2[l] = (_Float16)s2;
    }
    __syncthreads();

    const int xg = threadIdx.x & 7;     // 8 x-groups of 8 targets
    const int yg = threadIdx.x >> 3;    // 32 row-pairs
    const int ty_a = ty0 + 2 * yg;

    float aW[2][8], a0[2][8], a1[2][8], a2[2][8];
#pragma unroll
    for (int j = 0; j < 2; ++j)
#pragma unroll
        for (int i = 0; i < 8; ++i) { aW[j][i] = 0.f; a0[j][i] = 0.f;
                                      a1[j][i] = 0.f; a2[j][i] = 0.f; }

#pragma unroll 4
    for (int oy = 0; oy < 16; ++oy) {
        const float Cy = (float)(oy - 7);
        const int lrow = (2 * yg + oy) * PITCH + 8 * xg;   // even
#pragma unroll
        for (int oxp = 0; oxp < 11; ++oxp) {               // 22 cells = 11 pairs
            const int l = lrow + 2 * oxp;
            const h2 u2 = *(const h2*)(Up + l);
            const h2 v2 = *(const h2*)(Vp + l);
            const h2 s02 = *(const h2*)(P0 + l);
            const h2 s12 = *(const h2*)(P1 + l);
            const h2 s22 = *(const h2*)(P2 + l);

            f32x2 uf, vf;
            uf.x = (float)u2.x; uf.y = (float)u2.y;
            vf.x = (float)v2.x; vf.y = (float)v2.y;

            // ---- x chains, forward-only: dx0 = cell_x - target0_x + u ----
            const f32x2 kx = {(float)(2 * oxp - 7), (float)(2 * oxp - 6)};
            const f32x2 dx0 = uf + kx;
            const f32x2 aL = dx0 * (-LOG2E);
            const f32x2 axx = aL * dx0;
            const f32x2 s2m = aL + aL;
            f32x2 w[8];
            w[0].x = __builtin_amdgcn_exp2f(axx.x);     // exp(-dx0^2)
            w[0].y = __builtin_amdgcn_exp2f(axx.y);
            f32x2 G;
            G.x = __builtin_amdgcn_exp2f(-s2m.x);       // exp(2*dx0)
            G.y = __builtin_amdgcn_exp2f(-s2m.y);

#pragma unroll
            for (int i = 0; i < 7; ++i)
                w[i + 1] = w[i] * (G * CE[i]);

            h2 w2[8];
#pragma unroll
            for (int i = 0; i < 8; ++i)
                w2[i] = PKRTZ(w[i].x, w[i].y);

            // ---- y weights (rows a,b), direct exps ----
            const f32x2 dy  = vf + Cy;
            const f32x2 dyb = dy - 1.f;
            const f32x2 bL = dy * (-LOG2E);
            const f32x2 cL = dyb * (-LOG2E);
            const f32x2 ya = bL * dy;
            const f32x2 yb = cL * dyb;
            const float eyaA = __builtin_amdgcn_exp2f(ya.x);
            const float eyaB = __builtin_amdgcn_exp2f(ya.y);
            const float eybA = __builtin_amdgcn_exp2f(yb.x);
            const float eybB = __builtin_amdgcn_exp2f(yb.y);

            const h2 eya2 = PKRTZ(eyaA, eyaB);
            const h2 eyb2 = PKRTZ(eybA, eybB);
            const h2 z0a = s02 * eya2, z0b = s02 * eyb2;
            const h2 z1a = s12 * eya2, z1b = s12 * eyb2;
            const h2 z2a = s22 * eya2, z2b = s22 * eyb2;

#pragma unroll
            for (int i = 0; i < 8; ++i) {
                aW[0][i] = __builtin_amdgcn_fdot2(w2[i], eya2, aW[0][i], false);
                aW[1][i] = __builtin_amdgcn_fdot2(w2[i], eyb2, aW[1][i], false);
                a0[0][i] = __builtin_amdgcn_fdot2(w2[i], z0a, a0[0][i], false);
                a0[1][i] = __builtin_amdgcn_fdot2(w2[i], z0b, a0[1][i], false);
                a1[0][i] = __builtin_amdgcn_fdot2(w2[i], z1a, a1[0][i], false);
                a1[1][i] = __builtin_amdgcn_fdot2(w2[i], z1b, a1[1][i], false);
                a2[0][i] = __builtin_amdgcn_fdot2(w2[i], z2a, a2[0][i], false);
                a2[1][i] = __builtin_amdgcn_fdot2(w2[i], z2b, a2[1][i], false);
            }
        }
    }

    // Fused epilogue: add pre-splatted outlier contributions (already in out),
    // divide by (w+eps), write final image + mask. No finalize kernel.
    float* __restrict__ wI = out;
    float* __restrict__ wb = out + (size_t)B_N * C_N * HW;
    const int gx0 = tx0 + 8 * xg;
#pragma unroll
    for (int j = 0; j < 2; ++j) {
        const int ty = ty_a + j;
        if (ty >= H_IMG) continue;
        const int tb = ty * W_IMG + gx0;              // 16B-aligned
        float* p0 = wI + (size_t)(b * 3 + 0) * HW + tb;
        float* p1 = wI + (size_t)(b * 3 + 1) * HW + tb;
        float* p2 = wI + (size_t)(b * 3 + 2) * HW + tb;
        float* pw = wb + (size_t)b * HW + tb;
#pragma unroll
    for (int h = 0; h < 2; ++h) {                 // two float4 halves
            const float4 q0 = *(float4*)(p0 + 4 * h);
            const float4 q1 = *(float4*)(p1 + 4 * h);
            const float4 q2 = *(float4*)(p2 + 4 * h);
            const float4 qw = *(float4*)(pw + 4 * h);
            float wv[4] = {qw.x + aW[j][4*h+0], qw.y + aW[j][4*h+1],
                           qw.z + aW[j][4*h+2], qw.w + aW[j][4*h+3]};
            float inv[4];
#pragma unroll
            for (int t = 0; t < 4; ++t) inv[t] = 1.0f / (wv[t] + 1e-8f);
            *(float4*)(p0 + 4 * h) = make_float4(
                (q0.x + a0[j][4*h+0]) * inv[0], (q0.y + a0[j][4*h+1]) * inv[1],
                (q0.z + a0[j][4*h+2]) * inv[2], (q0.w + a0[j][4*h+3]) * inv[3]);
            *(float4*)(p1 + 4 * h) = make_float4(
                (q1.x + a1[j][4*h+0]) * inv[0], (q1.y + a1[j][4*h+1]) * inv[1],
                (q1.z + a1[j][4*h+2]) * inv[2], (q1.w + a1[j][4*h+3]) * inv[3]);
            *(float4*)(p2 + 4 * h) = make_float4(
                (q2.x + a2[j][4*h+0]) * inv[0], (q2.y + a2[j][4*h+1]) * inv[1],
                (q2.z + a2[j][4*h+2]) * inv[2], (q2.w + a2[j][4*h+3]) * inv[3]);
            *(float4*)(pw + 4 * h) = make_float4(
                wv[0] > 0.f ? 1.f : 0.f, wv[1] > 0.f ? 1.f : 0.f,
                wv[2] > 0.f ? 1.f : 0.f, wv[3] > 0.f ? 1.f : 0.f);
        }
    }
}

// Exact splat for rare sources with |u|>3.5 or |v|>3.5 (~9e-4 of pixels).
// Runs BEFORE gather on the zeroed out buffer; gather adds these in.
__global__ __launch_bounds__(256)
void outlier_kernel(const float* __restrict__ src, const float* __restrict__ flow,
                    float* __restrict__ out) {
    const int n4 = B_N * HW / 4;
    const int i4 = blockIdx.x * 256 + threadIdx.x;
    if (i4 >= n4) return;
    const int per_b = HW / 4;
    const int b = i4 / per_b;
    const int g0 = (i4 - b * per_b) * 4;
    const float* __restrict__ up = flow + (size_t)(b * 2) * HW;
    const float4 u4 = *(const float4*)(up + g0);
    const float4 v4 = *(const float4*)(up + HW + g0);
    const float um = fmaxf(fmaxf(fabsf(u4.x), fabsf(u4.y)), fmaxf(fabsf(u4.z), fabsf(u4.w)));
    const float vm = fmaxf(fmaxf(fabsf(v4.x), fabsf(v4.y)), fmaxf(fabsf(v4.z), fabsf(v4.w)));
    if (um <= FLOW_MAX && vm <= FLOW_MAX) return;

    const float uu[4] = {u4.x, u4.y, u4.z, u4.w};
    const float vv[4] = {v4.x, v4.y, v4.z, v4.w};
    const float* __restrict__ sp = src + (size_t)(b * 3) * HW;
    float* __restrict__ wI = out;
    float* __restrict__ wb = out + (size_t)B_N * C_N * HW;

    for (int k = 0; k < 4; ++k) {
        const float u = uu[k], v = vv[k];
        if (fabsf(u) <= FLOW_MAX && fabsf(v) <= FLOW_MAX) continue;
        const int g = g0 + k;
        const int x = g % W_IMG, y = g / W_IMG;
        const float px = (float)x + u, py = (float)y + v;
        if (!(px > -6.f && px < (float)W_IMG + 5.f &&
              py > -6.f && py < (float)H_IMG + 5.f)) continue;

        const float bxf = floorf(px), byf = floorf(py);
        const int bx = (int)bxf, by = (int)byf;
        const float s0 = sp[g], s1 = sp[HW + g], s2 = sp[2 * HW + g];

        for (int dyi = -4; dyi <= 4; ++dyi) {
            const int tyy = by + dyi;
            if (tyy < 0 || tyy >= H_IMG) continue;
            const float dyf = (byf + (float)dyi) - py;
            const float dy2 = dyf * dyf;
            for (int dxi = -4; dxi <= 4; ++dxi) {
                const int txx = bx + dxi;
                if (txx < 0 || txx >= W_IMG) continue;
                const float dxf = (bxf + (float)dxi) - px;
                const float d2 = fmaf(dxf, dxf, dy2);
                if (d2 > 16.f) continue;
                const float w = __expf(-d2);
                const int t = tyy * W_IMG + txx;
                atomicAdd(&wb[(size_t)b * HW + t], w);
                atomicAdd(&wI[(size_t)(b * 3 + 0) * HW + t], w * s0);
                atomicAdd(&wI[(size_t)(b * 3 + 1) * HW + t], w * s1);
                atomicAdd(&wI[(size_t)(b * 3 + 2) * HW + t], w * s2);
            }
        }
    }
}

extern "C" void kernel_launch(void* const* d_in, const int* in_sizes, int n_in,
                              void* d_out, int out_size, void* d_ws, size_t ws_size,
                              hipStream_t stream) {
    const float* src = (const float*)d_in[0];    // (4,3,720,1280) fp32
    const float* flow = (const float*)d_in[1];   // (4,2,720,1280) fp32
    float* out = (float*)d_out;                  // img (4,3,HW) ++ mask (4,1,HW)

    // 1) zero accumulators (out is poisoned 0xAA before every timed launch)
    (void)hipMemsetAsync(d_out, 0, (size_t)out_size * sizeof(float), stream);

    // 2) pre-splat rare large-flow sources with global atomics
    const int n4 = B_N * HW / 4;
    outlier_kernel<<<(n4 + 255) / 256, 256, 0, stream>>>(src, flow, out);

    // 3) gather everything else; fused add-prior + divide + mask epilogue
    dim3 grid(W_IMG / TW, (H_IMG + TH - 1) / TH, B_N);   // 20 x 12 x 4
    gather_kernel<<<grid, 256, 0, stream>>>(src, flow, out);
}